// Round 9
// baseline (276.446 us; speedup 1.0000x reference)
//
#include <hip/hip_runtime.h>
#include <hip/hip_bf16.h>
#include <hip/hip_fp16.h>
#include <math.h>

// Qwen2 decoder layer, MI355X. Round 9: single-pass down-proj (no split-K,
// no addreduce), vectorized prep_weights stores. Rest = R8.
// B=2 S=2048 D=1024 H=16 HKV=4 HD=64 FF=4096 WINDOW=1024
#define BB 2
#define SS 2048
#define DD 1024
#define HH 16
#define HKVN 4
#define HDIM 64
#define FFD 4096
#define WND 1024
#define EPSF 1e-6f

typedef _Float16 f16;
typedef _Float16 half8 __attribute__((ext_vector_type(8)));
typedef float f32x4 __attribute__((ext_vector_type(4)));
typedef unsigned int u32;

#define GLOAD_LDS(gp, lp)                                                  \
  __builtin_amdgcn_global_load_lds(                                        \
      (const __attribute__((address_space(1))) u32*)(gp),                  \
      (__attribute__((address_space(3))) u32*)(lp), 16, 0, 0)

static __device__ inline u32 pack2(float a, float b) {
  unsigned short ua = __builtin_bit_cast(unsigned short, (f16)a);
  unsigned short ub = __builtin_bit_cast(unsigned short, (f16)b);
  return (u32)ua | ((u32)ub << 16);
}

// ---------------- merged weight prep: 7 transposes + bias concat ----------
// tiles (64x64): wq[0,256) wk[256,320) wv[320,384) wo[384,640) wg[640,1664)
// wu[1664,2688) wd[2688,3712); bias blocks [3712,3718)
__global__ __launch_bounds__(256) void prep_weights_kernel(
    const float* __restrict__ wq, const float* __restrict__ wk,
    const float* __restrict__ wv, const float* __restrict__ wo,
    const float* __restrict__ wg, const float* __restrict__ wu,
    const float* __restrict__ wd, const float* __restrict__ bq,
    const float* __restrict__ bk, const float* __restrict__ bv,
    f16* __restrict__ qkvT, f16* __restrict__ woT, f16* __restrict__ wgT,
    f16* __restrict__ wuT, f16* __restrict__ wdT, float* __restrict__ biasC) {
  int t = blockIdx.x;
  if (t >= 3712) {
    int i = (t - 3712) * 256 + threadIdx.x;
    if (i < 1024)
      biasC[i] = bq[i];
    else if (i < 1280)
      biasC[i] = bk[i - 1024];
    else if (i < 1536)
      biasC[i] = bv[i - 1280];
    return;
  }
  const float* W;
  f16* Wt;
  int K, N, lt;
  if (t < 256) {
    W = wq; Wt = qkvT; K = 1024; N = 1024; lt = t;
  } else if (t < 320) {
    W = wk; Wt = qkvT + (size_t)1024 * 1024; K = 1024; N = 256; lt = t - 256;
  } else if (t < 384) {
    W = wv; Wt = qkvT + (size_t)1280 * 1024; K = 1024; N = 256; lt = t - 320;
  } else if (t < 640) {
    W = wo; Wt = woT; K = 1024; N = 1024; lt = t - 384;
  } else if (t < 1664) {
    W = wg; Wt = wgT; K = 1024; N = 4096; lt = t - 640;
  } else if (t < 2688) {
    W = wu; Wt = wuT; K = 1024; N = 4096; lt = t - 1664;
  } else {
    W = wd; Wt = wdT; K = 4096; N = 1024; lt = t - 2688;
  }
  int ntx = N >> 6;
  int n0 = (lt % ntx) * 64, k0 = (lt / ntx) * 64;
  __shared__ float tile[64][65];
  int tx = threadIdx.x & 63, tr = threadIdx.x >> 6;
#pragma unroll
  for (int i = 0; i < 16; i++) {
    int r = tr + i * 4;
    tile[r][tx] = W[(size_t)(k0 + r) * N + n0 + tx];
  }
  __syncthreads();
  // write: pack 2 consecutive k per u32 store (tile is [k][n])
  int kx = (threadIdx.x & 31) * 2;
  int rr = threadIdx.x >> 5;  // 0..7
#pragma unroll
  for (int i = 0; i < 8; i++) {
    int r = rr + i * 8;  // n-local
    u32 w = pack2(tile[kx][r], tile[kx + 1][r]);
    *(u32*)(Wt + (size_t)(n0 + r) * K + k0 + kx) = w;
  }
}

// ---------------- RMSNorm (D=1024): float4 loads, packed f16 stores --------
__global__ __launch_bounds__(256) void rmsnorm_kernel(
    const float* __restrict__ x, const float* __restrict__ w,
    f16* __restrict__ out) {
  int row = blockIdx.x;
  int tid = threadIdx.x;
  float4 v = ((const float4*)(x + (size_t)row * 1024))[tid];
  float ss = v.x * v.x + v.y * v.y + v.z * v.z + v.w * v.w;
  for (int o = 32; o > 0; o >>= 1) ss += __shfl_down(ss, o, 64);
  __shared__ float red[4];
  int wid = tid >> 6, lane = tid & 63;
  if (lane == 0) red[wid] = ss;
  __syncthreads();
  if (tid == 0)
    red[0] = rsqrtf((red[0] + red[1] + red[2] + red[3]) / 1024.f + EPSF);
  __syncthreads();
  float rs = red[0];
  float4 wv = ((const float4*)w)[tid];
  u32 lo = pack2(v.x * rs * wv.x, v.y * rs * wv.y);
  u32 hi = pack2(v.z * rs * wv.z, v.w * rs * wv.w);
  *(int2*)(out + (size_t)row * 1024 + tid * 4) = make_int2((int)lo, (int)hi);
}

// ---------------- f16 MFMA GEMM, 128x128, 4 waves, 3-buffer pipeline ------
// C = A[M][K] @ Bt[N][K]^T. Output: Ch(f16,+bias) or Cf(fp32,+bias/+resid).
__global__ __launch_bounds__(256) void mfma_gemm(
    const f16* __restrict__ A, const f16* __restrict__ Bt,
    const float* __restrict__ bias, const float* __restrict__ resid,
    float* __restrict__ Cf, f16* __restrict__ Ch, int M, int N, int K) {
  __shared__ __align__(16) char smem[3 * 16384];
  const int tid = threadIdx.x;
  const int lane = tid & 63;
  const int wid = tid >> 6;
  const int wr = wid >> 1, wc = wid & 1;
  const int row0 = blockIdx.y * 128, col0 = blockIdx.x * 128;

  f32x4 acc[4][4];
#pragma unroll
  for (int m = 0; m < 4; m++)
#pragma unroll
    for (int n = 0; n < 4; n++) acc[m][n] = (f32x4){0.f, 0.f, 0.f, 0.f};

  auto stage = [&](int buf, int k0) {
    char* base = smem + buf * 16384;
#pragma unroll
    for (int q = 0; q < 2; q++) {
      int s = wid * 128 + q * 64 + lane;
      int r = s >> 2;
      int cg = (s & 3) ^ ((r >> 1) & 3);
      size_t goff = (size_t)r * K + k0 + cg * 8;
      u32 ldsb = (u32)((wid * 2 + q) * 1024);
      GLOAD_LDS(A + (size_t)row0 * K + goff, base + ldsb);
      GLOAD_LDS(Bt + (size_t)col0 * K + goff, base + 8192 + ldsb);
    }
  };
  auto off = [&](int r, int g) -> int {
    return r * 64 + ((g ^ ((r >> 1) & 3)) << 4);
  };

  const int nt = K / 32;
  stage(0, 0);
  if (nt > 1) stage(1, 32);
  int cur = 0;
  const int g = lane >> 4, l15 = lane & 15;
  for (int t = 0; t < nt; t++) {
    if (t + 1 < nt)
      asm volatile("s_waitcnt vmcnt(4)" ::: "memory");
    else
      asm volatile("s_waitcnt vmcnt(0)" ::: "memory");
    asm volatile("s_waitcnt lgkmcnt(0)" ::: "memory");
    __builtin_amdgcn_sched_barrier(0);
    __builtin_amdgcn_s_barrier();
    __builtin_amdgcn_sched_barrier(0);
    const char* base = smem + cur * 16384;
    half8 af[4], bf[4];
#pragma unroll
    for (int m = 0; m < 4; m++) {
      int r = wr * 64 + m * 16 + l15;
      af[m] = *(const half8*)(base + off(r, g));
    }
#pragma unroll
    for (int n = 0; n < 4; n++) {
      int c = wc * 64 + n * 16 + l15;
      bf[n] = *(const half8*)(base + 8192 + off(c, g));
    }
    if (t + 2 < nt) {
      int nb = cur + 2;
      if (nb >= 3) nb -= 3;
      stage(nb, (t + 2) * 32);
    }
    __builtin_amdgcn_s_setprio(1);
#pragma unroll
    for (int m = 0; m < 4; m++)
#pragma unroll
      for (int n = 0; n < 4; n++)
        acc[m][n] =
            __builtin_amdgcn_mfma_f32_16x16x32_f16(af[m], bf[n], acc[m][n], 0, 0, 0);
    __builtin_amdgcn_s_setprio(0);
    cur = (cur + 1 == 3) ? 0 : cur + 1;
  }

#pragma unroll
  for (int m = 0; m < 4; m++) {
#pragma unroll
    for (int n = 0; n < 4; n++) {
#pragma unroll
      for (int v = 0; v < 4; v++) {
        int r = row0 + wr * 64 + m * 16 + (lane >> 4) * 4 + v;
        int c = col0 + wc * 64 + n * 16 + l15;
        float vv = acc[m][n][v];
        if (bias) vv += bias[c];
        if (Ch) {
          Ch[(size_t)r * N + c] = (f16)vv;
        } else {
          if (resid) vv += resid[(size_t)r * N + c];
          Cf[(size_t)r * N + c] = vv;
        }
      }
    }
  }
}

// ---------------- gate/up dual GEMM: 128x256 tile, 8 waves, 64x64 ----------
__global__ __launch_bounds__(512) void gateup_gemm(
    const f16* __restrict__ A, const f16* __restrict__ Wg,
    const f16* __restrict__ Wu, f16* __restrict__ ACT, int M, int N, int K) {
  __shared__ __align__(16) char smem[3 * 40960];
  const int tid = threadIdx.x;
  const int lane = tid & 63;
  const int wid = tid >> 6;  // 0..7
  const int wr = wid >> 2;   // 0..1
  const int wc = wid & 3;    // 0..3
  const int row0 = blockIdx.y * 128, col0 = blockIdx.x * 256;

  f32x4 accg[4][4], accu[4][4];
#pragma unroll
  for (int m = 0; m < 4; m++)
#pragma unroll
    for (int n = 0; n < 4; n++) {
      accg[m][n] = (f32x4){0.f, 0.f, 0.f, 0.f};
      accu[m][n] = (f32x4){0.f, 0.f, 0.f, 0.f};
    }

  auto stage = [&](int buf, int k0) {
    char* base = smem + buf * 40960;
    {
      int s = tid;
      int r = s >> 2;
      int cg = (s & 3) ^ ((r >> 1) & 3);
      size_t goff = (size_t)r * K + k0 + cg * 8;
      GLOAD_LDS(A + (size_t)row0 * K + goff, base + wid * 1024);
    }
#pragma unroll
    for (int p = 0; p < 2; p++) {
      int s = p * 512 + tid;
      int r = s >> 2;
      int cg = (s & 3) ^ ((r >> 1) & 3);
      size_t goff = (size_t)r * K + k0 + cg * 8;
      GLOAD_LDS(Wg + (size_t)col0 * K + goff,
                base + 8192 + p * 8192 + wid * 1024);
    }
#pragma unroll
    for (int p = 0; p < 2; p++) {
      int s = p * 512 + tid;
      int r = s >> 2;
      int cg = (s & 3) ^ ((r >> 1) & 3);
      size_t goff = (size_t)r * K + k0 + cg * 8;
      GLOAD_LDS(Wu + (size_t)col0 * K + goff,
                base + 24576 + p * 8192 + wid * 1024);
    }
  };
  auto off = [&](int r, int g) -> int {
    return r * 64 + ((g ^ ((r >> 1) & 3)) << 4);
  };

  const int nt = K / 32;
  stage(0, 0);
  if (nt > 1) stage(1, 32);
  int cur = 0;
  const int g = lane >> 4, l15 = lane & 15;
  for (int t = 0; t < nt; t++) {
    if (t + 1 < nt)
      asm volatile("s_waitcnt vmcnt(5)" ::: "memory");
    else
      asm volatile("s_waitcnt vmcnt(0)" ::: "memory");
    asm volatile("s_waitcnt lgkmcnt(0)" ::: "memory");
    __builtin_amdgcn_sched_barrier(0);
    __builtin_amdgcn_s_barrier();
    __builtin_amdgcn_sched_barrier(0);
    const char* base = smem + cur * 40960;
    half8 af[4], gf[4], uf[4];
#pragma unroll
    for (int m = 0; m < 4; m++) {
      int r = wr * 64 + m * 16 + l15;
      af[m] = *(const half8*)(base + off(r, g));
    }
#pragma unroll
    for (int n = 0; n < 4; n++) {
      int c = wc * 64 + n * 16 + l15;
      gf[n] = *(const half8*)(base + 8192 + off(c, g));
      uf[n] = *(const half8*)(base + 24576 + off(c, g));
    }
    if (t + 2 < nt) {
      int nb = cur + 2;
      if (nb >= 3) nb -= 3;
      stage(nb, (t + 2) * 32);
    }
    __builtin_amdgcn_s_setprio(1);
#pragma unroll
    for (int m = 0; m < 4; m++)
#pragma unroll
      for (int n = 0; n < 4; n++) {
        accg[m][n] =
            __builtin_amdgcn_mfma_f32_16x16x32_f16(af[m], gf[n], accg[m][n], 0, 0, 0);
        accu[m][n] =
            __builtin_amdgcn_mfma_f32_16x16x32_f16(af[m], uf[n], accu[m][n], 0, 0, 0);
      }
    __builtin_amdgcn_s_setprio(0);
    cur = (cur + 1 == 3) ? 0 : cur + 1;
  }

#pragma unroll
  for (int m = 0; m < 4; m++) {
#pragma unroll
    for (int n = 0; n < 4; n++) {
#pragma unroll
      for (int v = 0; v < 4; v++) {
        int r = row0 + wr * 64 + m * 16 + (lane >> 4) * 4 + v;
        int c = col0 + wc * 64 + n * 16 + l15;
        float gg = accg[m][n][v];
        float uu = accu[m][n][v];
        float sv = gg / (1.f + __expf(-gg));
        ACT[(size_t)r * N + c] = (f16)(sv * uu);
      }
    }
  }
}

// ---------------- RoPE + cast from fused QKV [M][1536] f16 ----------------
__global__ __launch_bounds__(256) void rope_cast_kernel(
    const f16* __restrict__ QKV, const float* __restrict__ cos_t,
    const float* __restrict__ sin_t, f16* __restrict__ Qh,
    f16* __restrict__ Kh) {
  int idx = blockIdx.x * blockDim.x + threadIdx.x;
  int d = idx & 31;
  int rest = idx >> 5;
  int head = rest % (HH + HKVN);
  int bs = rest / (HH + HKVN);
  int s = bs % SS;
  float c = cos_t[s * HDIM + d];
  float sn = sin_t[s * HDIM + d];
  const f16* rowp = QKV + (size_t)bs * 1536;
  if (head < HH) {
    const f16* base = rowp + head * HDIM;
    float x1 = (float)base[d], x2 = (float)base[d + 32];
    f16* ob = Qh + ((size_t)bs * HH + head) * HDIM;
    ob[d] = (f16)((x1 * c - x2 * sn) * 0.125f);
    ob[d + 32] = (f16)((x2 * c + x1 * sn) * 0.125f);
  } else {
    int hk = head - HH;
    const f16* base = rowp + 1024 + hk * HDIM;
    float x1 = (float)base[d], x2 = (float)base[d + 32];
    f16* ob = Kh + ((size_t)bs * HKVN + hk) * HDIM;
    ob[d] = (f16)(x1 * c - x2 * sn);
    ob[d + 32] = (f16)(x2 * c + x1 * sn);
  }
}

// ---------------- V transpose from QKV f16 cols 1280..1535 ----------------
__global__ __launch_bounds__(256) void vtrans_kernel(
    const f16* __restrict__ QKV, f16* __restrict__ Vt) {
  __shared__ f16 tile[64][72];
  int st = blockIdx.x & 31;
  int hk = (blockIdx.x >> 5) & 3;
  int b = blockIdx.x >> 7;
  int s0 = st * 64;
  int tid = threadIdx.x;
  int r = tid >> 2, cg = tid & 3;
#pragma unroll
  for (int i = 0; i < 2; i++) {
    const f16* src = QKV + (size_t)(b * SS + s0 + r) * 1536 + 1280 + hk * HDIM +
                     cg * 16 + i * 8;
    *(int4*)&tile[r][cg * 16 + i * 8] = *(const int4*)src;  // 8 halves = 16B
  }
  __syncthreads();
  int dd = tid >> 2, sg = tid & 3;
#pragma unroll
  for (int i = 0; i < 4; i++) {
    int c0 = sg * 16 + i * 4;
    unsigned short a0 = __builtin_bit_cast(unsigned short, tile[c0 + 0][dd]);
    unsigned short a1 = __builtin_bit_cast(unsigned short, tile[c0 + 1][dd]);
    unsigned short a2 = __builtin_bit_cast(unsigned short, tile[c0 + 2][dd]);
    unsigned short a3 = __builtin_bit_cast(unsigned short, tile[c0 + 3][dd]);
    u32 w0 = (u32)a0 | ((u32)a1 << 16);
    u32 w1 = (u32)a2 | ((u32)a3 << 16);
    *(int2*)(Vt + ((size_t)(b * HKVN + hk) * HDIM + dd) * SS + s0 + c0) =
        make_int2((int)w0, (int)w1);
  }
}

// ---------------- Flash attention, MFMA 16x16x32 f16 (R4) ----------------
__global__ __launch_bounds__(256) void attn_kernel(
    const f16* __restrict__ Qh, const f16* __restrict__ Kh,
    const f16* __restrict__ Vt, f16* __restrict__ O) {
  __shared__ __align__(16) char smem[2 * 16384 + 4 * 4608];
  const int tid = threadIdx.x;
  const int lane = tid & 63;
  const int wid = tid >> 6;
  const int l15 = lane & 15;
  const int g = lane >> 4;
  int qt = blockIdx.x & 63;
  int hk = (blockIdx.x >> 6) & 3;
  int b = blockIdx.x >> 8;
  int s0 = qt * 32;
  int h = hk * 4 + wid;

  half8 qf[2][2];
#pragma unroll
  for (int n = 0; n < 2; n++) {
    int q = s0 + n * 16 + l15;
    const f16* qp = Qh + (((size_t)b * SS + q) * HH + h) * HDIM;
#pragma unroll
    for (int kk = 0; kk < 2; kk++) qf[n][kk] = *(const half8*)(qp + kk * 32 + g * 8);
  }

  const int tb = (s0 >= WND) ? ((s0 - (WND - 1)) >> 6) : 0;
  const int te = (s0 + 31) >> 6;

  f32x4 acc_o[2][4];
#pragma unroll
  for (int m2 = 0; m2 < 2; m2++)
#pragma unroll
    for (int n = 0; n < 4; n++) acc_o[m2][n] = (f32x4){0.f, 0.f, 0.f, 0.f};
  float mrun[2] = {-1e30f, -1e30f};
  float lrun[2] = {0.f, 0.f};

  char* pw = smem + 32768 + wid * 4608;

  auto stage = [&](int buf, int tt) {
    int jt0 = tt * 64;
    char* kbase = smem + buf * 16384;
#pragma unroll
    for (int q2 = 0; q2 < 2; q2++) {
      int slot = (wid * 2 + q2) * 64 + lane;
      int r = slot >> 3, c = slot & 7;
      int cc = c ^ (r & 7);
      u32 ldsb = (u32)((wid * 2 + q2) * 1024);
      const f16* gk =
          Kh + ((size_t)(b * SS + jt0 + r) * HKVN + hk) * HDIM + cc * 8;
      GLOAD_LDS(gk, kbase + ldsb);
      const f16* gv =
          Vt + ((size_t)(b * HKVN + hk) * HDIM + r) * SS + jt0 + cc * 8;
      GLOAD_LDS(gv, kbase + 8192 + ldsb);
    }
  };

  stage(0, tb);
  __syncthreads();
  for (int tt = tb; tt <= te; tt++) {
    int buf = (tt - tb) & 1;
    if (tt < te) stage(buf ^ 1, tt + 1);
    const char* kb = smem + buf * 16384;
    const char* vbp = kb + 8192;
    int jt0 = tt * 64;

    f32x4 acc_s[4][2];
#pragma unroll
    for (int m = 0; m < 4; m++)
#pragma unroll
      for (int n = 0; n < 2; n++) acc_s[m][n] = (f32x4){0.f, 0.f, 0.f, 0.f};
#pragma unroll
    for (int kk = 0; kk < 2; kk++) {
      half8 af[4];
#pragma unroll
      for (int m = 0; m < 4; m++) {
        int key = m * 16 + l15;
        af[m] = *(const half8*)(kb + key * 128 + (((kk * 4 + g) ^ (key & 7)) << 4));
      }
#pragma unroll
      for (int m = 0; m < 4; m++)
#pragma unroll
        for (int n = 0; n < 2; n++)
          acc_s[m][n] = __builtin_amdgcn_mfma_f32_16x16x32_f16(af[m], qf[n][kk],
                                                               acc_s[m][n], 0, 0, 0);
    }

    float tmax[2] = {-1e38f, -1e38f};
#pragma unroll
    for (int m = 0; m < 4; m++)
#pragma unroll
      for (int n = 0; n < 2; n++)
#pragma unroll
        for (int v = 0; v < 4; v++) {
          int j = jt0 + m * 16 + g * 4 + v;
          int q = s0 + n * 16 + l15;
          float s = acc_s[m][n][v];
          s = ((unsigned)(q - j) < (unsigned)WND) ? s : -1e38f;
          acc_s[m][n][v] = s;
          tmax[n] = fmaxf(tmax[n], s);
        }
#pragma unroll
    for (int n = 0; n < 2; n++) {
      tmax[n] = fmaxf(tmax[n], __shfl_xor(tmax[n], 16, 64));
      tmax[n] = fmaxf(tmax[n], __shfl_xor(tmax[n], 32, 64));
    }
    float corr[2], rs[2];
#pragma unroll
    for (int n = 0; n < 2; n++) {
      float mn = fmaxf(mrun[n], tmax[n]);
      corr[n] = __expf(mrun[n] - mn);
      mrun[n] = mn;
      rs[n] = 0.f;
    }
#pragma unroll
    for (int m = 0; m < 4; m++)
#pragma unroll
      for (int n = 0; n < 2; n++) {
        float p0 = __expf(acc_s[m][n][0] - mrun[n]);
        float p1 = __expf(acc_s[m][n][1] - mrun[n]);
        float p2 = __expf(acc_s[m][n][2] - mrun[n]);
        float p3 = __expf(acc_s[m][n][3] - mrun[n]);
        rs[n] += (p0 + p1) + (p2 + p3);
        *(int2*)(pw + (n * 16 + l15) * 144 + (m * 16 + g * 4) * 2) =
            make_int2((int)pack2(p0, p1), (int)pack2(p2, p3));
      }
#pragma unroll
    for (int n = 0; n < 2; n++) {
      rs[n] += __shfl_xor(rs[n], 16, 64);
      rs[n] += __shfl_xor(rs[n], 32, 64);
      lrun[n] = lrun[n] * corr[n] + rs[n];
    }
#pragma unroll
    for (int m2 = 0; m2 < 2; m2++)
#pragma unroll
      for (int v = 0; v < 4; v++) {
        float cw = __shfl(corr[m2], g * 4 + v, 64);
#pragma unroll
        for (int n = 0; n < 4; n++) acc_o[m2][n][v] *= cw;
      }
#pragma unroll
    for (int kk = 0; kk < 2; kk++) {
      half8 ap[2], vf[4];
#pragma unroll
      for (int m2 = 0; m2 < 2; m2++)
        ap[m2] = *(const half8*)(pw + (m2 * 16 + l15) * 144 + (kk * 32 + g * 8) * 2);
#pragma unroll
      for (int n = 0; n < 4; n++) {
        int d = n * 16 + l15;
        vf[n] = *(const half8*)(vbp + d * 128 + (((kk * 4 + g) ^ (d & 7)) << 4));
      }
#pragma unroll
      for (int m2 = 0; m2 < 2; m2++)
#pragma unroll
        for (int n = 0; n < 4; n++)
          acc_o[m2][n] = __builtin_amdgcn_mfma_f32_16x16x32_f16(ap[m2], vf[n],
                                                                acc_o[m2][n], 0, 0, 0);
    }
    __syncthreads();
  }

#pragma unroll
  for (int m2 = 0; m2 < 2; m2++)
#pragma unroll
    for (int v = 0; v < 4; v++) {
      float li = __shfl(lrun[m2], g * 4 + v, 64);
      float inv = 1.f / li;
      int q = s0 + m2 * 16 + g * 4 + v;
#pragma unroll
      for (int n = 0; n < 4; n++) {
        int d = n * 16 + l15;
        O[(((size_t)b * SS + q) * HH + h) * HDIM + d] =
            (f16)(acc_o[m2][n][v] * inv);
      }
    }
}

extern "C" void kernel_launch(void* const* d_in, const int* in_sizes, int n_in,
                              void* d_out, int out_size, void* d_ws,
                              size_t ws_size, hipStream_t stream) {
  const float* hidden = (const float*)d_in[0];
  const float* cos_t = (const float*)d_in[1];
  const float* sin_t = (const float*)d_in[2];
  const float* wq = (const float*)d_in[3];
  const float* bq = (const float*)d_in[4];
  const float* wk = (const float*)d_in[5];
  const float* bk = (const float*)d_in[6];
  const float* wv = (const float*)d_in[7];
  const float* bv = (const float*)d_in[8];
  const float* wo = (const float*)d_in[9];
  const float* ln1 = (const float*)d_in[10];
  const float* ln2 = (const float*)d_in[11];
  const float* wg = (const float*)d_in[12];
  const float* wu = (const float*)d_in[13];
  const float* wd = (const float*)d_in[14];
  float* out = (float*)d_out;
  char* ws = (char*)d_ws;

  const int M = BB * SS;  // 4096

  // workspace layout (MB offsets)
  f16* qkvT = (f16*)ws;                      // [1536][1024] 3MB
  f16* woT = (f16*)(ws + (3u << 20));        // 2MB
  f16* wgT = (f16*)(ws + (5u << 20));        // 8MB
  f16* wuT = (f16*)(ws + (13u << 20));       // 8MB
  f16* wdT = (f16*)(ws + (21u << 20));       // 8MB
  f16* Anh = (f16*)(ws + (29u << 20));       // 8MB
  f16* CTXh = (f16*)(ws + (37u << 20));      // 8MB
  f16* QKVh = (f16*)(ws + (45u << 20));      // [M][1536] 12MB (dead after rope/vtrans)
  f16* Qh = (f16*)(ws + (57u << 20));        // 8MB (dead after attn)
  f16* Kh = (f16*)(ws + (65u << 20));        // 2MB (dead after attn)
  f16* Vt = (f16*)(ws + (67u << 20));        // 2MB (dead after attn)
  f16* ACTh = (f16*)(ws + (45u << 20));      // 32MB (45-77), over QKVh..Vt (dead)
  float* biasC = (float*)(ws + (81u << 20)); // 6KB

  // 0) all weight transposes + bias concat in one launch
  prep_weights_kernel<<<3718, 256, 0, stream>>>(wq, wk, wv, wo, wg, wu, wd, bq,
                                                bk, bv, qkvT, woT, wgT, wuT,
                                                wdT, biasC);
  // 1) RMSNorm 1 -> f16
  rmsnorm_kernel<<<M, 256, 0, stream>>>(hidden, ln1, Anh);
  // 2) fused QKV projection -> f16 [M][1536] (+bias)
  mfma_gemm<<<dim3(1536 / 128, M / 128), 256, 0, stream>>>(
      Anh, qkvT, biasC, nullptr, nullptr, QKVh, M, 1536, DD);
  // 3) RoPE -> Qh (pre-scaled), Kh ; V -> Vt
  rope_cast_kernel<<<(BB * SS * (HH + HKVN) * 32) / 256, 256, 0, stream>>>(
      QKVh, cos_t, sin_t, Qh, Kh);
  vtrans_kernel<<<BB * HKVN * (SS / 64), 256, 0, stream>>>(QKVh, Vt);
  // 4) Flash attention -> f16 CTX
  attn_kernel<<<BB * HKVN * (SS / 32), 256, 0, stream>>>(Qh, Kh, Vt, CTXh);
  // 5) Output projection + residual -> d_out
  mfma_gemm<<<dim3(DD / 128, M / 128), 256, 0, stream>>>(
      CTXh, woT, nullptr, hidden, out, nullptr, M, DD, DD);
  // 6) RMSNorm 2 -> f16
  rmsnorm_kernel<<<M, 256, 0, stream>>>(out, ln2, Anh);
  // 7) gate/up dual GEMM + SiLU*up -> f16 ACT
  gateup_gemm<<<dim3(FFD / 256, M / 128), 512, 0, stream>>>(Anh, wgT, wuT, ACTh,
                                                            M, FFD, DD);
  // 8) MLP down-proj + residual2 -> d_out (single pass, K=4096)
  mfma_gemm<<<dim3(DD / 128, M / 128), 256, 0, stream>>>(
      ACTh, wdT, nullptr, out, out, nullptr, M, DD, FFD);
}

// Round 10
// 252.964 us; speedup vs baseline: 1.0928x; 1.0928x over previous
//
#include <hip/hip_runtime.h>
#include <hip/hip_bf16.h>
#include <hip/hip_fp16.h>
#include <math.h>

// Qwen2 decoder layer, MI355X. Round 10: gemm_n64 (512-block grids) for
// wo/down; RoPE fused into QKV epilogue (fp32 rotate). Rest = R9.
// B=2 S=2048 D=1024 H=16 HKV=4 HD=64 FF=4096 WINDOW=1024
#define BB 2
#define SS 2048
#define DD 1024
#define HH 16
#define HKVN 4
#define HDIM 64
#define FFD 4096
#define WND 1024
#define EPSF 1e-6f

typedef _Float16 f16;
typedef _Float16 half8 __attribute__((ext_vector_type(8)));
typedef float f32x4 __attribute__((ext_vector_type(4)));
typedef unsigned int u32;

#define GLOAD_LDS(gp, lp)                                                  \
  __builtin_amdgcn_global_load_lds(                                        \
      (const __attribute__((address_space(1))) u32*)(gp),                  \
      (__attribute__((address_space(3))) u32*)(lp), 16, 0, 0)

static __device__ inline u32 pack2(float a, float b) {
  unsigned short ua = __builtin_bit_cast(unsigned short, (f16)a);
  unsigned short ub = __builtin_bit_cast(unsigned short, (f16)b);
  return (u32)ua | ((u32)ub << 16);
}

// ---------------- merged weight prep: 7 transposes + bias concat ----------
__global__ __launch_bounds__(256) void prep_weights_kernel(
    const float* __restrict__ wq, const float* __restrict__ wk,
    const float* __restrict__ wv, const float* __restrict__ wo,
    const float* __restrict__ wg, const float* __restrict__ wu,
    const float* __restrict__ wd, const float* __restrict__ bq,
    const float* __restrict__ bk, const float* __restrict__ bv,
    f16* __restrict__ qkvT, f16* __restrict__ woT, f16* __restrict__ wgT,
    f16* __restrict__ wuT, f16* __restrict__ wdT, float* __restrict__ biasC) {
  int t = blockIdx.x;
  if (t >= 3712) {
    int i = (t - 3712) * 256 + threadIdx.x;
    if (i < 1024)
      biasC[i] = bq[i];
    else if (i < 1280)
      biasC[i] = bk[i - 1024];
    else if (i < 1536)
      biasC[i] = bv[i - 1280];
    return;
  }
  const float* W;
  f16* Wt;
  int K, N, lt;
  if (t < 256) {
    W = wq; Wt = qkvT; K = 1024; N = 1024; lt = t;
  } else if (t < 320) {
    W = wk; Wt = qkvT + (size_t)1024 * 1024; K = 1024; N = 256; lt = t - 256;
  } else if (t < 384) {
    W = wv; Wt = qkvT + (size_t)1280 * 1024; K = 1024; N = 256; lt = t - 320;
  } else if (t < 640) {
    W = wo; Wt = woT; K = 1024; N = 1024; lt = t - 384;
  } else if (t < 1664) {
    W = wg; Wt = wgT; K = 1024; N = 4096; lt = t - 640;
  } else if (t < 2688) {
    W = wu; Wt = wuT; K = 1024; N = 4096; lt = t - 1664;
  } else {
    W = wd; Wt = wdT; K = 4096; N = 1024; lt = t - 2688;
  }
  int ntx = N >> 6;
  int n0 = (lt % ntx) * 64, k0 = (lt / ntx) * 64;
  __shared__ float tile[64][65];
  int tx = threadIdx.x & 63, tr = threadIdx.x >> 6;
#pragma unroll
  for (int i = 0; i < 16; i++) {
    int r = tr + i * 4;
    tile[r][tx] = W[(size_t)(k0 + r) * N + n0 + tx];
  }
  __syncthreads();
  int kx = (threadIdx.x & 31) * 2;
  int rr = threadIdx.x >> 5;
#pragma unroll
  for (int i = 0; i < 8; i++) {
    int r = rr + i * 8;
    u32 w = pack2(tile[kx][r], tile[kx + 1][r]);
    *(u32*)(Wt + (size_t)(n0 + r) * K + k0 + kx) = w;
  }
}

// ---------------- RMSNorm (D=1024): float4 loads, packed f16 stores --------
__global__ __launch_bounds__(256) void rmsnorm_kernel(
    const float* __restrict__ x, const float* __restrict__ w,
    f16* __restrict__ out) {
  int row = blockIdx.x;
  int tid = threadIdx.x;
  float4 v = ((const float4*)(x + (size_t)row * 1024))[tid];
  float ss = v.x * v.x + v.y * v.y + v.z * v.z + v.w * v.w;
  for (int o = 32; o > 0; o >>= 1) ss += __shfl_down(ss, o, 64);
  __shared__ float red[4];
  int wid = tid >> 6, lane = tid & 63;
  if (lane == 0) red[wid] = ss;
  __syncthreads();
  if (tid == 0)
    red[0] = rsqrtf((red[0] + red[1] + red[2] + red[3]) / 1024.f + EPSF);
  __syncthreads();
  float rs = red[0];
  float4 wv = ((const float4*)w)[tid];
  u32 lo = pack2(v.x * rs * wv.x, v.y * rs * wv.y);
  u32 hi = pack2(v.z * rs * wv.z, v.w * rs * wv.w);
  *(int2*)(out + (size_t)row * 1024 + tid * 4) = make_int2((int)lo, (int)hi);
}

// ---------------- QKV GEMM (128x128, 4 waves, 3-buffer) + fused RoPE ------
// A[M][1024] @ qkvT[1536][1024]^T + biasC. Epilogue per col-tile type:
// Q cols [0,1024): rope (fp32) + 0.125 scale -> Qh; K cols [1024,1280):
// rope -> Kh; V cols [1280,1536): -> compact Vh [M][256].
__global__ __launch_bounds__(256) void qkv_gemm(
    const f16* __restrict__ A, const f16* __restrict__ Bt,
    const float* __restrict__ biasC, const float* __restrict__ cos_t,
    const float* __restrict__ sin_t, f16* __restrict__ Qh,
    f16* __restrict__ Kh, f16* __restrict__ Vh, int M, int N, int K) {
  __shared__ __align__(16) char smem[3 * 16384];
  const int tid = threadIdx.x;
  const int lane = tid & 63;
  const int wid = tid >> 6;
  const int wr = wid >> 1, wc = wid & 1;
  const int row0 = blockIdx.y * 128, col0 = blockIdx.x * 128;

  f32x4 acc[4][4];
#pragma unroll
  for (int m = 0; m < 4; m++)
#pragma unroll
    for (int n = 0; n < 4; n++) acc[m][n] = (f32x4){0.f, 0.f, 0.f, 0.f};

  auto stage = [&](int buf, int k0) {
    char* base = smem + buf * 16384;
#pragma unroll
    for (int q = 0; q < 2; q++) {
      int s = wid * 128 + q * 64 + lane;
      int r = s >> 2;
      int cg = (s & 3) ^ ((r >> 1) & 3);
      size_t goff = (size_t)r * K + k0 + cg * 8;
      u32 ldsb = (u32)((wid * 2 + q) * 1024);
      GLOAD_LDS(A + (size_t)row0 * K + goff, base + ldsb);
      GLOAD_LDS(Bt + (size_t)col0 * K + goff, base + 8192 + ldsb);
    }
  };
  auto off = [&](int r, int g) -> int {
    return r * 64 + ((g ^ ((r >> 1) & 3)) << 4);
  };

  const int nt = K / 32;
  stage(0, 0);
  if (nt > 1) stage(1, 32);
  int cur = 0;
  const int g = lane >> 4, l15 = lane & 15;
  for (int t = 0; t < nt; t++) {
    if (t + 1 < nt)
      asm volatile("s_waitcnt vmcnt(4)" ::: "memory");
    else
      asm volatile("s_waitcnt vmcnt(0)" ::: "memory");
    asm volatile("s_waitcnt lgkmcnt(0)" ::: "memory");
    __builtin_amdgcn_sched_barrier(0);
    __builtin_amdgcn_s_barrier();
    __builtin_amdgcn_sched_barrier(0);
    const char* base = smem + cur * 16384;
    half8 af[4], bf[4];
#pragma unroll
    for (int m = 0; m < 4; m++) {
      int r = wr * 64 + m * 16 + l15;
      af[m] = *(const half8*)(base + off(r, g));
    }
#pragma unroll
    for (int n = 0; n < 4; n++) {
      int c = wc * 64 + n * 16 + l15;
      bf[n] = *(const half8*)(base + 8192 + off(c, g));
    }
    if (t + 2 < nt) {
      int nb = cur + 2;
      if (nb >= 3) nb -= 3;
      stage(nb, (t + 2) * 32);
    }
    __builtin_amdgcn_s_setprio(1);
#pragma unroll
    for (int m = 0; m < 4; m++)
#pragma unroll
      for (int n = 0; n < 4; n++)
        acc[m][n] =
            __builtin_amdgcn_mfma_f32_16x16x32_f16(af[m], bf[n], acc[m][n], 0, 0, 0);
    __builtin_amdgcn_s_setprio(0);
    cur = (cur + 1 == 3) ? 0 : cur + 1;
  }

  // epilogue: block-uniform type by col0
  const int typ = (col0 < 1024) ? 0 : (col0 < 1280 ? 1 : 2);
#pragma unroll
  for (int m = 0; m < 4; m++) {
#pragma unroll
    for (int v = 0; v < 4; v++) {
      int r = row0 + wr * 64 + m * 16 + (lane >> 4) * 4 + v;
      int s = r & (SS - 1);
      if (typ == 2) {
#pragma unroll
        for (int n = 0; n < 4; n++) {
          int c = col0 + wc * 64 + n * 16 + l15;
          float vv = acc[m][n][v] + biasC[c];
          Vh[(size_t)r * 256 + (c - 1280)] = (f16)vv;
        }
      } else {
#pragma unroll
        for (int n = 0; n < 2; n++) {
          int d = n * 16 + l15;  // < 32
          int c1 = col0 + wc * 64 + d;
          float x1 = acc[m][n][v] + biasC[c1];
          float x2 = acc[m][n + 2][v] + biasC[c1 + 32];
          float cv = cos_t[s * HDIM + d];
          float sv = sin_t[s * HDIM + d];
          float o1 = x1 * cv - x2 * sv;
          float o2 = x2 * cv + x1 * sv;  // cos/sin duplicated halves
          if (typ == 0) {
            int h = c1 >> 6;
            f16* qp = Qh + ((size_t)r * HH + h) * HDIM + d;
            qp[0] = (f16)(o1 * 0.125f);
            qp[32] = (f16)(o2 * 0.125f);
          } else {
            int hk = (c1 - 1024) >> 6;
            f16* kp = Kh + ((size_t)r * HKVN + hk) * HDIM + d;
            kp[0] = (f16)o1;
            kp[32] = (f16)o2;
          }
        }
      }
    }
  }
}

// ---------------- gemm_n64: BM=128, BN=64, 4 waves (64x32), fp32+resid ----
// C[r][c] = A@Bt^T + resid. Grid (N/64, M/128) -> 512 blocks for N=1024.
__global__ __launch_bounds__(256) void gemm_n64(
    const f16* __restrict__ A, const f16* __restrict__ Bt,
    const float* __restrict__ resid, float* __restrict__ Cf, int M, int N,
    int K) {
  __shared__ __align__(16) char smem[3 * 12288];
  const int tid = threadIdx.x;
  const int lane = tid & 63;
  const int wid = tid >> 6;
  const int wr = wid >> 1, wc = wid & 1;
  const int row0 = blockIdx.y * 128, col0 = blockIdx.x * 64;

  f32x4 acc[4][2];
#pragma unroll
  for (int m = 0; m < 4; m++)
#pragma unroll
    for (int n = 0; n < 2; n++) acc[m][n] = (f32x4){0.f, 0.f, 0.f, 0.f};

  auto stage = [&](int buf, int k0) {
    char* base = smem + buf * 12288;
#pragma unroll
    for (int p = 0; p < 2; p++) {  // A: 128 rows x 64B
      int s = p * 256 + tid;
      int r = s >> 2;
      int cg = (s & 3) ^ ((r >> 1) & 3);
      size_t goff = (size_t)r * K + k0 + cg * 8;
      GLOAD_LDS(A + (size_t)row0 * K + goff, base + p * 4096 + wid * 1024);
    }
    {  // B: 64 rows x 64B
      int s = tid;
      int r = s >> 2;
      int cg = (s & 3) ^ ((r >> 1) & 3);
      size_t goff = (size_t)r * K + k0 + cg * 8;
      GLOAD_LDS(Bt + (size_t)col0 * K + goff, base + 8192 + wid * 1024);
    }
  };
  auto off = [&](int r, int g) -> int {
    return r * 64 + ((g ^ ((r >> 1) & 3)) << 4);
  };

  const int nt = K / 32;
  stage(0, 0);
  if (nt > 1) stage(1, 32);
  int cur = 0;
  const int g = lane >> 4, l15 = lane & 15;
  for (int t = 0; t < nt; t++) {
    if (t + 1 < nt)
      asm volatile("s_waitcnt vmcnt(3)" ::: "memory");
    else
      asm volatile("s_waitcnt vmcnt(0)" ::: "memory");
    asm volatile("s_waitcnt lgkmcnt(0)" ::: "memory");
    __builtin_amdgcn_sched_barrier(0);
    __builtin_amdgcn_s_barrier();
    __builtin_amdgcn_sched_barrier(0);
    const char* base = smem + cur * 12288;
    half8 af[4], bf[2];
#pragma unroll
    for (int m = 0; m < 4; m++) {
      int r = wr * 64 + m * 16 + l15;
      af[m] = *(const half8*)(base + off(r, g));
    }
#pragma unroll
    for (int n = 0; n < 2; n++) {
      int c = wc * 32 + n * 16 + l15;
      bf[n] = *(const half8*)(base + 8192 + off(c, g));
    }
    if (t + 2 < nt) {
      int nb = cur + 2;
      if (nb >= 3) nb -= 3;
      stage(nb, (t + 2) * 32);
    }
    __builtin_amdgcn_s_setprio(1);
#pragma unroll
    for (int m = 0; m < 4; m++)
#pragma unroll
      for (int n = 0; n < 2; n++)
        acc[m][n] =
            __builtin_amdgcn_mfma_f32_16x16x32_f16(af[m], bf[n], acc[m][n], 0, 0, 0);
    __builtin_amdgcn_s_setprio(0);
    cur = (cur + 1 == 3) ? 0 : cur + 1;
  }

#pragma unroll
  for (int m = 0; m < 4; m++) {
#pragma unroll
    for (int n = 0; n < 2; n++) {
#pragma unroll
      for (int v = 0; v < 4; v++) {
        int r = row0 + wr * 64 + m * 16 + (lane >> 4) * 4 + v;
        int c = col0 + wc * 32 + n * 16 + l15;
        float vv = acc[m][n][v] + resid[(size_t)r * N + c];
        Cf[(size_t)r * N + c] = vv;
      }
    }
  }
}

// ---------------- gate/up dual GEMM: 128x256 tile, 8 waves, 64x64 ----------
__global__ __launch_bounds__(512) void gateup_gemm(
    const f16* __restrict__ A, const f16* __restrict__ Wg,
    const f16* __restrict__ Wu, f16* __restrict__ ACT, int M, int N, int K) {
  __shared__ __align__(16) char smem[3 * 40960];
  const int tid = threadIdx.x;
  const int lane = tid & 63;
  const int wid = tid >> 6;
  const int wr = wid >> 2;
  const int wc = wid & 3;
  const int row0 = blockIdx.y * 128, col0 = blockIdx.x * 256;

  f32x4 accg[4][4], accu[4][4];
#pragma unroll
  for (int m = 0; m < 4; m++)
#pragma unroll
    for (int n = 0; n < 4; n++) {
      accg[m][n] = (f32x4){0.f, 0.f, 0.f, 0.f};
      accu[m][n] = (f32x4){0.f, 0.f, 0.f, 0.f};
    }

  auto stage = [&](int buf, int k0) {
    char* base = smem + buf * 40960;
    {
      int s = tid;
      int r = s >> 2;
      int cg = (s & 3) ^ ((r >> 1) & 3);
      size_t goff = (size_t)r * K + k0 + cg * 8;
      GLOAD_LDS(A + (size_t)row0 * K + goff, base + wid * 1024);
    }
#pragma unroll
    for (int p = 0; p < 2; p++) {
      int s = p * 512 + tid;
      int r = s >> 2;
      int cg = (s & 3) ^ ((r >> 1) & 3);
      size_t goff = (size_t)r * K + k0 + cg * 8;
      GLOAD_LDS(Wg + (size_t)col0 * K + goff,
                base + 8192 + p * 8192 + wid * 1024);
    }
#pragma unroll
    for (int p = 0; p < 2; p++) {
      int s = p * 512 + tid;
      int r = s >> 2;
      int cg = (s & 3) ^ ((r >> 1) & 3);
      size_t goff = (size_t)r * K + k0 + cg * 8;
      GLOAD_LDS(Wu + (size_t)col0 * K + goff,
                base + 24576 + p * 8192 + wid * 1024);
    }
  };
  auto off = [&](int r, int g) -> int {
    return r * 64 + ((g ^ ((r >> 1) & 3)) << 4);
  };

  const int nt = K / 32;
  stage(0, 0);
  if (nt > 1) stage(1, 32);
  int cur = 0;
  const int g = lane >> 4, l15 = lane & 15;
  for (int t = 0; t < nt; t++) {
    if (t + 1 < nt)
      asm volatile("s_waitcnt vmcnt(5)" ::: "memory");
    else
      asm volatile("s_waitcnt vmcnt(0)" ::: "memory");
    asm volatile("s_waitcnt lgkmcnt(0)" ::: "memory");
    __builtin_amdgcn_sched_barrier(0);
    __builtin_amdgcn_s_barrier();
    __builtin_amdgcn_sched_barrier(0);
    const char* base = smem + cur * 40960;
    half8 af[4], gf[4], uf[4];
#pragma unroll
    for (int m = 0; m < 4; m++) {
      int r = wr * 64 + m * 16 + l15;
      af[m] = *(const half8*)(base + off(r, g));
    }
#pragma unroll
    for (int n = 0; n < 4; n++) {
      int c = wc * 64 + n * 16 + l15;
      gf[n] = *(const half8*)(base + 8192 + off(c, g));
      uf[n] = *(const half8*)(base + 24576 + off(c, g));
    }
    if (t + 2 < nt) {
      int nb = cur + 2;
      if (nb >= 3) nb -= 3;
      stage(nb, (t + 2) * 32);
    }
    __builtin_amdgcn_s_setprio(1);
#pragma unroll
    for (int m = 0; m < 4; m++)
#pragma unroll
      for (int n = 0; n < 4; n++) {
        accg[m][n] =
            __builtin_amdgcn_mfma_f32_16x16x32_f16(af[m], gf[n], accg[m][n], 0, 0, 0);
        accu[m][n] =
            __builtin_amdgcn_mfma_f32_16x16x32_f16(af[m], uf[n], accu[m][n], 0, 0, 0);
      }
    __builtin_amdgcn_s_setprio(0);
    cur = (cur + 1 == 3) ? 0 : cur + 1;
  }

#pragma unroll
  for (int m = 0; m < 4; m++) {
#pragma unroll
    for (int n = 0; n < 4; n++) {
#pragma unroll
      for (int v = 0; v < 4; v++) {
        int r = row0 + wr * 64 + m * 16 + (lane >> 4) * 4 + v;
        int c = col0 + wc * 64 + n * 16 + l15;
        float gg = accg[m][n][v];
        float uu = accu[m][n][v];
        float sv = gg / (1.f + __expf(-gg));
        ACT[(size_t)r * N + c] = (f16)(sv * uu);
      }
    }
  }
}

// ---------------- V transpose from compact Vh [M][256] ----------------
__global__ __launch_bounds__(256) void vtrans_kernel(
    const f16* __restrict__ Vh, f16* __restrict__ Vt) {
  __shared__ f16 tile[64][72];
  int st = blockIdx.x & 31;
  int hk = (blockIdx.x >> 5) & 3;
  int b = blockIdx.x >> 7;
  int s0 = st * 64;
  int tid = threadIdx.x;
  int r = tid >> 2, cg = tid & 3;
#pragma unroll
  for (int i = 0; i < 2; i++) {
    const f16* src =
        Vh + (size_t)(b * SS + s0 + r) * 256 + hk * HDIM + cg * 16 + i * 8;
    *(int4*)&tile[r][cg * 16 + i * 8] = *(const int4*)src;
  }
  __syncthreads();
  int dd = tid >> 2, sg = tid & 3;
#pragma unroll
  for (int i = 0; i < 4; i++) {
    int c0 = sg * 16 + i * 4;
    unsigned short a0 = __builtin_bit_cast(unsigned short, tile[c0 + 0][dd]);
    unsigned short a1 = __builtin_bit_cast(unsigned short, tile[c0 + 1][dd]);
    unsigned short a2 = __builtin_bit_cast(unsigned short, tile[c0 + 2][dd]);
    unsigned short a3 = __builtin_bit_cast(unsigned short, tile[c0 + 3][dd]);
    u32 w0 = (u32)a0 | ((u32)a1 << 16);
    u32 w1 = (u32)a2 | ((u32)a3 << 16);
    *(int2*)(Vt + ((size_t)(b * HKVN + hk) * HDIM + dd) * SS + s0 + c0) =
        make_int2((int)w0, (int)w1);
  }
}

// ---------------- Flash attention, MFMA 16x16x32 f16 (R4) ----------------
__global__ __launch_bounds__(256) void attn_kernel(
    const f16* __restrict__ Qh, const f16* __restrict__ Kh,
    const f16* __restrict__ Vt, f16* __restrict__ O) {
  __shared__ __align__(16) char smem[2 * 16384 + 4 * 4608];
  const int tid = threadIdx.x;
  const int lane = tid & 63;
  const int wid = tid >> 6;
  const int l15 = lane & 15;
  const int g = lane >> 4;
  int qt = blockIdx.x & 63;
  int hk = (blockIdx.x >> 6) & 3;
  int b = blockIdx.x >> 8;
  int s0 = qt * 32;
  int h = hk * 4 + wid;

  half8 qf[2][2];
#pragma unroll
  for (int n = 0; n < 2; n++) {
    int q = s0 + n * 16 + l15;
    const f16* qp = Qh + (((size_t)b * SS + q) * HH + h) * HDIM;
#pragma unroll
    for (int kk = 0; kk < 2; kk++) qf[n][kk] = *(const half8*)(qp + kk * 32 + g * 8);
  }

  const int tb = (s0 >= WND) ? ((s0 - (WND - 1)) >> 6) : 0;
  const int te = (s0 + 31) >> 6;

  f32x4 acc_o[2][4];
#pragma unroll
  for (int m2 = 0; m2 < 2; m2++)
#pragma unroll
    for (int n = 0; n < 4; n++) acc_o[m2][n] = (f32x4){0.f, 0.f, 0.f, 0.f};
  float mrun[2] = {-1e30f, -1e30f};
  float lrun[2] = {0.f, 0.f};

  char* pw = smem + 32768 + wid * 4608;

  auto stage = [&](int buf, int tt) {
    int jt0 = tt * 64;
    char* kbase = smem + buf * 16384;
#pragma unroll
    for (int q2 = 0; q2 < 2; q2++) {
      int slot = (wid * 2 + q2) * 64 + lane;
      int r = slot >> 3, c = slot & 7;
      int cc = c ^ (r & 7);
      u32 ldsb = (u32)((wid * 2 + q2) * 1024);
      const f16* gk =
          Kh + ((size_t)(b * SS + jt0 + r) * HKVN + hk) * HDIM + cc * 8;
      GLOAD_LDS(gk, kbase + ldsb);
      const f16* gv =
          Vt + ((size_t)(b * HKVN + hk) * HDIM + r) * SS + jt0 + cc * 8;
      GLOAD_LDS(gv, kbase + 8192 + ldsb);
    }
  };

  stage(0, tb);
  __syncthreads();
  for (int tt = tb; tt <= te; tt++) {
    int buf = (tt - tb) & 1;
    if (tt < te) stage(buf ^ 1, tt + 1);
    const char* kb = smem + buf * 16384;
    const char* vbp = kb + 8192;
    int jt0 = tt * 64;

    f32x4 acc_s[4][2];
#pragma unroll
    for (int m = 0; m < 4; m++)
#pragma unroll
      for (int n = 0; n < 2; n++) acc_s[m][n] = (f32x4){0.f, 0.f, 0.f, 0.f};
#pragma unroll
    for (int kk = 0; kk < 2; kk++) {
      half8 af[4];
#pragma unroll
      for (int m = 0; m < 4; m++) {
        int key = m * 16 + l15;
        af[m] = *(const half8*)(kb + key * 128 + (((kk * 4 + g) ^ (key & 7)) << 4));
      }
#pragma unroll
      for (int m = 0; m < 4; m++)
#pragma unroll
        for (int n = 0; n < 2; n++)
          acc_s[m][n] = __builtin_amdgcn_mfma_f32_16x16x32_f16(af[m], qf[n][kk],
                                                               acc_s[m][n], 0, 0, 0);
    }

    float tmax[2] = {-1e38f, -1e38f};
#pragma unroll
    for (int m = 0; m < 4; m++)
#pragma unroll
      for (int n = 0; n < 2; n++)
#pragma unroll
        for (int v = 0; v < 4; v++) {
          int j = jt0 + m * 16 + g * 4 + v;
          int q = s0 + n * 16 + l15;
          float s = acc_s[m][n][v];
          s = ((unsigned)(q - j) < (unsigned)WND) ? s : -1e38f;
          acc_s[m][n][v] = s;
          tmax[n] = fmaxf(tmax[n], s);
        }
#pragma unroll
    for (int n = 0; n < 2; n++) {
      tmax[n] = fmaxf(tmax[n], __shfl_xor(tmax[n], 16, 64));
      tmax[n] = fmaxf(tmax[n], __shfl_xor(tmax[n], 32, 64));
    }
    float corr[2], rs[2];
#pragma unroll
    for (int n = 0; n < 2; n++) {
      float mn = fmaxf(mrun[n], tmax[n]);
      corr[n] = __expf(mrun[n] - mn);
      mrun[n] = mn;
      rs[n] = 0.f;
    }
#pragma unroll
    for (int m = 0; m < 4; m++)
#pragma unroll
      for (int n = 0; n < 2; n++) {
        float p0 = __expf(acc_s[m][n][0] - mrun[n]);
        float p1 = __expf(acc_s[m][n][1] - mrun[n]);
        float p2 = __expf(acc_s[m][n][2] - mrun[n]);
        float p3 = __expf(acc_s[m][n][3] - mrun[n]);
        rs[n] += (p0 + p1) + (p2 + p3);
        *(int2*)(pw + (n * 16 + l15) * 144 + (m * 16 + g * 4) * 2) =
            make_int2((int)pack2(p0, p1), (int)pack2(p2, p3));
      }
#pragma unroll
    for (int n = 0; n < 2; n++) {
      rs[n] += __shfl_xor(rs[n], 16, 64);
      rs[n] += __shfl_xor(rs[n], 32, 64);
      lrun[n] = lrun[n] * corr[n] + rs[n];
    }
#pragma unroll
    for (int m2 = 0; m2 < 2; m2++)
#pragma unroll
      for (int v = 0; v < 4; v++) {
        float cw = __shfl(corr[m2], g * 4 + v, 64);
#pragma unroll
        for (int n = 0; n < 4; n++) acc_o[m2][n][v] *= cw;
      }
#pragma unroll
    for (int kk = 0; kk < 2; kk++) {
      half8 ap[2], vf[4];
#pragma unroll
      for (int m2 = 0; m2 < 2; m2++)
        ap[m2] = *(const half8*)(pw + (m2 * 16 + l15) * 144 + (kk * 32 + g * 8) * 2);
#pragma unroll
      for (int n = 0; n < 4; n++) {
        int d = n * 16 + l15;
        vf[n] = *(const half8*)(vbp + d * 128 + (((kk * 4 + g) ^ (d & 7)) << 4));
      }
#pragma unroll
      for (int m2 = 0; m2 < 2; m2++)
#pragma unroll
        for (int n = 0; n < 4; n++)
          acc_o[m2][n] = __builtin_amdgcn_mfma_f32_16x16x32_f16(ap[m2], vf[n],
                                                                acc_o[m2][n], 0, 0, 0);
    }
    __syncthreads();
  }

#pragma unroll
  for (int m2 = 0; m2 < 2; m2++)
#pragma unroll
    for (int v = 0; v < 4; v++) {
      float li = __shfl(lrun[m2], g * 4 + v, 64);
      float inv = 1.f / li;
      int q = s0 + m2 * 16 + g * 4 + v;
#pragma unroll
      for (int n = 0; n < 4; n++) {
        int d = n * 16 + l15;
        O[(((size_t)b * SS + q) * HH + h) * HDIM + d] =
            (f16)(acc_o[m2][n][v] * inv);
      }
    }
}

extern "C" void kernel_launch(void* const* d_in, const int* in_sizes, int n_in,
                              void* d_out, int out_size, void* d_ws,
                              size_t ws_size, hipStream_t stream) {
  const float* hidden = (const float*)d_in[0];
  const float* cos_t = (const float*)d_in[1];
  const float* sin_t = (const float*)d_in[2];
  const float* wq = (const float*)d_in[3];
  const float* bq = (const float*)d_in[4];
  const float* wk = (const float*)d_in[5];
  const float* bk = (const float*)d_in[6];
  const float* wv = (const float*)d_in[7];
  const float* bv = (const float*)d_in[8];
  const float* wo = (const float*)d_in[9];
  const float* ln1 = (const float*)d_in[10];
  const float* ln2 = (const float*)d_in[11];
  const float* wg = (const float*)d_in[12];
  const float* wu = (const float*)d_in[13];
  const float* wd = (const float*)d_in[14];
  float* out = (float*)d_out;
  char* ws = (char*)d_ws;

  const int M = BB * SS;  // 4096

  // workspace layout (MB offsets)
  f16* qkvT = (f16*)ws;                      // [1536][1024] 3MB
  f16* woT = (f16*)(ws + (3u << 20));        // 2MB
  f16* wgT = (f16*)(ws + (5u << 20));        // 8MB
  f16* wuT = (f16*)(ws + (13u << 20));       // 8MB
  f16* wdT = (f16*)(ws + (21u << 20));       // 8MB
  f16* Anh = (f16*)(ws + (29u << 20));       // 8MB
  f16* CTXh = (f16*)(ws + (37u << 20));      // 8MB
  f16* Vh = (f16*)(ws + (45u << 20));        // [M][256] 2MB (dead after vtrans)
  f16* Qh = (f16*)(ws + (57u << 20));        // 8MB (dead after attn)
  f16* Kh = (f16*)(ws + (65u << 20));        // 2MB (dead after attn)
  f16* Vt = (f16*)(ws + (67u << 20));        // 2MB (dead after attn)
  f16* ACTh = (f16*)(ws + (45u << 20));      // 32MB (45-77), over Vh..Vt (dead)
  float* biasC = (float*)(ws + (81u << 20)); // 6KB

  // 0) all weight transposes + bias concat in one launch
  prep_weights_kernel<<<3718, 256, 0, stream>>>(wq, wk, wv, wo, wg, wu, wd, bq,
                                                bk, bv, qkvT, woT, wgT, wuT,
                                                wdT, biasC);
  // 1) RMSNorm 1 -> f16
  rmsnorm_kernel<<<M, 256, 0, stream>>>(hidden, ln1, Anh);
  // 2) fused QKV projection + bias + RoPE -> Qh (scaled), Kh, Vh
  qkv_gemm<<<dim3(1536 / 128, M / 128), 256, 0, stream>>>(
      Anh, qkvT, biasC, cos_t, sin_t, Qh, Kh, Vh, M, 1536, DD);
  // 3) V transpose
  vtrans_kernel<<<BB * HKVN * (SS / 64), 256, 0, stream>>>(Vh, Vt);
  // 4) Flash attention -> f16 CTX
  attn_kernel<<<BB * HKVN * (SS / 32), 256, 0, stream>>>(Qh, Kh, Vt, CTXh);
  // 5) Output projection + residual -> d_out (512 blocks)
  gemm_n64<<<dim3(DD / 64, M / 128), 256, 0, stream>>>(CTXh, woT, hidden, out,
                                                       M, DD, DD);
  // 6) RMSNorm 2 -> f16
  rmsnorm_kernel<<<M, 256, 0, stream>>>(out, ln2, Anh);
  // 7) gate/up dual GEMM + SiLU*up -> f16 ACT
  gateup_gemm<<<dim3(FFD / 256, M / 128), 512, 0, stream>>>(Anh, wgT, wuT, ACTh,
                                                            M, FFD, DD);
  // 8) MLP down-proj + residual2 -> d_out (512 blocks, K=4096)
  gemm_n64<<<dim3(DD / 64, M / 128), 256, 0, stream>>>(ACTh, wdT, out, out, M,
                                                       DD, FFD);
}